// Round 3
// baseline (215.302 us; speedup 1.0000x reference)
//
#include <hip/hip_runtime.h>

// YOLO v1 loss, two-kernel fused reduction (no global atomics).
// input_: [B, 30, 7, 7] fp32   (channel-major per image)
// target: [B, 7, 7, 30] fp32   (cell-major, 30 contiguous per cell)
// out   : [1] fp32 scalar loss
//
// Kernel 1: 2 cells/thread, direct loads (input: 30 coalesced dwords/cell;
// target: 15 float2/cell, 8B-aligned), block partial -> d_ws (plain store).
// Kernel 2: one block reduces the partials, writes out = sum/B.
// No atomics, no inter-phase barriers -> maximize loads in flight.

#define CELLF   64.0f
#define IMGF    448.0f
#define EPSF    1e-6f
#define LAMBDA_COORD 5.0f
#define LAMBDA_NOOBJ 0.5f

#define TPB 256
#define CPT 2                 // cells per thread
#define CPB (TPB * CPT)       // 512 cells per block

__device__ __forceinline__ float cell_loss(const float* __restrict__ input,
                                           const float* __restrict__ target,
                                           int n)
{
    const int b    = n / 49;
    const int cell = n - b * 49;
    const int row  = cell / 7;
    const int col  = cell - row * 7;

    // ---- loads (all independent; 30 dwords + 15 float2 in flight) ----
    const float* xin = input + (size_t)b * 1470 + cell;
    float x[30];
    #pragma unroll
    for (int c = 0; c < 30; ++c) x[c] = xin[c * 49];

    const float2* tp = reinterpret_cast<const float2*>(target + (size_t)n * 30);
    float t[30];
    #pragma unroll
    for (int j = 0; j < 15; ++j) {
        float2 v = tp[j];
        t[2 * j]     = v.x;
        t[2 * j + 1] = v.y;
    }

    const float colf = (float)col * CELLF;
    const float rowf = (float)row * CELLF;

    float iou[2];
    #pragma unroll
    for (int k = 0; k < 2; ++k) {
        const int o = 5 * k;
        float pcx = x[o + 0] * CELLF + colf;
        float pcy = x[o + 1] * CELLF + rowf;
        float pw  = x[o + 2] * IMGF;
        float ph  = x[o + 3] * IMGF;
        float px1 = fminf(fmaxf(pcx - 0.5f * pw, 0.0f), IMGF);
        float py1 = fminf(fmaxf(pcy - 0.5f * ph, 0.0f), IMGF);
        float px2 = fminf(fmaxf(pcx + 0.5f * pw, 0.0f), IMGF);
        float py2 = fminf(fmaxf(pcy + 0.5f * ph, 0.0f), IMGF);

        float tcx = t[o + 0] * CELLF + colf;
        float tcy = t[o + 1] * CELLF + rowf;
        float tw  = t[o + 2] * IMGF;
        float th  = t[o + 3] * IMGF;
        float tx1 = fminf(fmaxf(tcx - 0.5f * tw, 0.0f), IMGF);
        float ty1 = fminf(fmaxf(tcy - 0.5f * th, 0.0f), IMGF);
        float tx2 = fminf(fmaxf(tcx + 0.5f * tw, 0.0f), IMGF);
        float ty2 = fminf(fmaxf(tcy + 0.5f * th, 0.0f), IMGF);

        float iw = fmaxf(fminf(px2, tx2) - fmaxf(px1, tx1), EPSF);
        float ih = fmaxf(fminf(py2, ty2) - fmaxf(py1, ty1), EPSF);
        float inter = iw * ih;
        float area  = (px2 - px1) * (py2 - py1) + (tx2 - tx1) * (ty2 - ty1);
        iou[k] = inter / (area - inter);
    }

    const bool  m      = iou[0] < iou[1];
    const float iouSel = m ? iou[1] : iou[0];
    const float has_obj = (t[4] == 1.0f) ? 1.0f : 0.0f;
    const float no_obj  = 1.0f - has_obj;

    const float s0 = m ? x[5] : x[0];
    const float s1 = m ? x[6] : x[1];
    const float s2 = m ? x[7] : x[2];
    const float s3 = m ? x[8] : x[3];
    const float s4 = m ? x[9] : x[4];

    float d0 = s0 - t[0], d1 = s1 - t[1];
    float coord_e = d0 * d0 + d1 * d1;

    float e2 = sqrtf(s2) - sqrtf(t[2]);
    float e3 = sqrtf(s3) - sqrtf(t[3]);
    float size_e = e2 * e2 + e3 * e3;

    float dc = s4 - iouSel;
    float conf_e = dc * dc;

    float cls_e = 0.0f;
    #pragma unroll
    for (int c = 10; c < 30; ++c) {
        float d = x[c] - t[c];
        cls_e += d * d;
    }

    float noobj_e = x[4] * x[4] + x[9] * x[9];

    return has_obj * (LAMBDA_COORD * coord_e + LAMBDA_COORD * size_e + conf_e + cls_e)
         + LAMBDA_NOOBJ * no_obj * noobj_e;
}

__global__ __launch_bounds__(TPB) void yolo_main(
    const float* __restrict__ input,
    const float* __restrict__ target,
    float* __restrict__ partial,
    int ncells)
{
    const int tid  = threadIdx.x;
    const int base = blockIdx.x * CPB;

    float acc = 0.0f;
    #pragma unroll
    for (int it = 0; it < CPT; ++it) {
        const int n = base + it * TPB + tid;
        if (n < ncells) acc += cell_loss(input, target, n);
    }

    // wave shuffle reduce (width 64), then cross-wave via LDS
    #pragma unroll
    for (int off = 32; off > 0; off >>= 1)
        acc += __shfl_down(acc, off, 64);

    __shared__ float s_part[TPB / 64];
    if ((tid & 63) == 0) s_part[tid >> 6] = acc;
    __syncthreads();

    if (tid == 0) {
        float tot = 0.0f;
        #pragma unroll
        for (int w = 0; w < TPB / 64; ++w) tot += s_part[w];
        partial[blockIdx.x] = tot;
    }
}

__global__ __launch_bounds__(256) void yolo_reduce(
    const float* __restrict__ partial, int nparts,
    float* __restrict__ out, float inv_b)
{
    const int tid = threadIdx.x;
    float v = 0.0f;
    for (int i = tid; i < nparts; i += 256) v += partial[i];

    #pragma unroll
    for (int off = 32; off > 0; off >>= 1)
        v += __shfl_down(v, off, 64);

    __shared__ float s_part[4];
    if ((tid & 63) == 0) s_part[tid >> 6] = v;
    __syncthreads();

    if (tid == 0)
        out[0] = (s_part[0] + s_part[1] + s_part[2] + s_part[3]) * inv_b;
}

extern "C" void kernel_launch(void* const* d_in, const int* in_sizes, int n_in,
                              void* d_out, int out_size, void* d_ws, size_t ws_size,
                              hipStream_t stream) {
    const float* input  = (const float*)d_in[0];
    const float* target = (const float*)d_in[1];
    float* out = (float*)d_out;
    float* partial = (float*)d_ws;

    const int B = in_sizes[0] / (30 * 49);      // 16384
    const int ncells = B * 49;                  // 802816
    const int nblocks = (ncells + CPB - 1) / CPB;  // 1568

    yolo_main<<<nblocks, TPB, 0, stream>>>(input, target, partial, ncells);
    yolo_reduce<<<1, 256, 0, stream>>>(partial, nblocks, out, 1.0f / (float)B);
}

// Round 4
// 206.220 us; speedup vs baseline: 1.0440x; 1.0440x over previous
//
#include <hip/hip_runtime.h>

// YOLO v1 loss, two-kernel fused reduction.
// input_: [B, 30, 7, 7] fp32   (channel-major per image)
// target: [B, 7, 7, 30] fp32   (cell-major, 30 contiguous per cell)
// out   : [1] fp32 scalar loss
//
// Round-4 change: issue ALL 45 loads per cell into registers BEFORE any math,
// fenced with sched_barrier(0) so the compiler can't sink loads to their uses
// (Round-3 showed VGPR=32 => loads serialized, 1-2 in flight, 1.4 TB/s).
// Deliberately spend ~100 VGPRs to keep 45 loads/wave outstanding.

#define CELLF   64.0f
#define IMGF    448.0f
#define EPSF    1e-6f
#define LAMBDA_COORD 5.0f
#define LAMBDA_NOOBJ 0.5f

#define TPB 256

__global__ __launch_bounds__(TPB) void yolo_main(
    const float* __restrict__ input,
    const float* __restrict__ target,
    float* __restrict__ partial,
    int ncells)
{
    const int tid = threadIdx.x;
    const int n   = blockIdx.x * TPB + tid;

    float lv = 0.0f;
    if (n < ncells) {
        const int b    = n / 49;
        const int cell = n - b * 49;
        const int row  = cell / 7;
        const int col  = cell - row * 7;

        // ---- issue ALL loads first (30 dwords + 15 float2), keep in regs ----
        const float* xin = input + (size_t)b * 1470 + cell;
        float x[30];
        #pragma unroll
        for (int c = 0; c < 30; ++c) x[c] = xin[c * 49];

        const float2* tp = reinterpret_cast<const float2*>(target + (size_t)n * 30);
        float t[30];
        #pragma unroll
        for (int j = 0; j < 15; ++j) {
            float2 v = tp[j];
            t[2 * j]     = v.x;
            t[2 * j + 1] = v.y;
        }

        // fence: nothing below may be hoisted above / loads may not sink below
        __builtin_amdgcn_sched_barrier(0);

        const float colf = (float)col * CELLF;
        const float rowf = (float)row * CELLF;

        float iou[2];
        #pragma unroll
        for (int k = 0; k < 2; ++k) {
            const int o = 5 * k;
            float pcx = x[o + 0] * CELLF + colf;
            float pcy = x[o + 1] * CELLF + rowf;
            float pw  = x[o + 2] * IMGF;
            float ph  = x[o + 3] * IMGF;
            float px1 = fminf(fmaxf(pcx - 0.5f * pw, 0.0f), IMGF);
            float py1 = fminf(fmaxf(pcy - 0.5f * ph, 0.0f), IMGF);
            float px2 = fminf(fmaxf(pcx + 0.5f * pw, 0.0f), IMGF);
            float py2 = fminf(fmaxf(pcy + 0.5f * ph, 0.0f), IMGF);

            float tcx = t[o + 0] * CELLF + colf;
            float tcy = t[o + 1] * CELLF + rowf;
            float tw  = t[o + 2] * IMGF;
            float th  = t[o + 3] * IMGF;
            float tx1 = fminf(fmaxf(tcx - 0.5f * tw, 0.0f), IMGF);
            float ty1 = fminf(fmaxf(tcy - 0.5f * th, 0.0f), IMGF);
            float tx2 = fminf(fmaxf(tcx + 0.5f * tw, 0.0f), IMGF);
            float ty2 = fminf(fmaxf(tcy + 0.5f * th, 0.0f), IMGF);

            float iw = fmaxf(fminf(px2, tx2) - fmaxf(px1, tx1), EPSF);
            float ih = fmaxf(fminf(py2, ty2) - fmaxf(py1, ty1), EPSF);
            float inter = iw * ih;
            float area  = (px2 - px1) * (py2 - py1) + (tx2 - tx1) * (ty2 - ty1);
            iou[k] = inter / (area - inter);
        }

        const bool  m      = iou[0] < iou[1];
        const float iouSel = m ? iou[1] : iou[0];
        const float has_obj = (t[4] == 1.0f) ? 1.0f : 0.0f;
        const float no_obj  = 1.0f - has_obj;

        const float s0 = m ? x[5] : x[0];
        const float s1 = m ? x[6] : x[1];
        const float s2 = m ? x[7] : x[2];
        const float s3 = m ? x[8] : x[3];
        const float s4 = m ? x[9] : x[4];

        float d0 = s0 - t[0], d1 = s1 - t[1];
        float coord_e = d0 * d0 + d1 * d1;

        float e2 = sqrtf(s2) - sqrtf(t[2]);
        float e3 = sqrtf(s3) - sqrtf(t[3]);
        float size_e = e2 * e2 + e3 * e3;

        float dc = s4 - iouSel;
        float conf_e = dc * dc;

        float cls_e = 0.0f;
        #pragma unroll
        for (int c = 10; c < 30; ++c) {
            float d = x[c] - t[c];
            cls_e += d * d;
        }

        float noobj_e = x[4] * x[4] + x[9] * x[9];

        lv = has_obj * (LAMBDA_COORD * coord_e + LAMBDA_COORD * size_e + conf_e + cls_e)
           + LAMBDA_NOOBJ * no_obj * noobj_e;
    }

    // ---- reduce: wave shuffle, then cross-wave via LDS ----
    #pragma unroll
    for (int off = 32; off > 0; off >>= 1)
        lv += __shfl_down(lv, off, 64);

    __shared__ float s_part[TPB / 64];
    if ((tid & 63) == 0) s_part[tid >> 6] = lv;
    __syncthreads();

    if (tid == 0) {
        float tot = 0.0f;
        #pragma unroll
        for (int w = 0; w < TPB / 64; ++w) tot += s_part[w];
        partial[blockIdx.x] = tot;
    }
}

__global__ __launch_bounds__(256) void yolo_reduce(
    const float* __restrict__ partial, int nparts,
    float* __restrict__ out, float inv_b)
{
    const int tid = threadIdx.x;
    float v = 0.0f;
    for (int i = tid; i < nparts; i += 256) v += partial[i];

    #pragma unroll
    for (int off = 32; off > 0; off >>= 1)
        v += __shfl_down(v, off, 64);

    __shared__ float s_part[4];
    if ((tid & 63) == 0) s_part[tid >> 6] = v;
    __syncthreads();

    if (tid == 0)
        out[0] = (s_part[0] + s_part[1] + s_part[2] + s_part[3]) * inv_b;
}

extern "C" void kernel_launch(void* const* d_in, const int* in_sizes, int n_in,
                              void* d_out, int out_size, void* d_ws, size_t ws_size,
                              hipStream_t stream) {
    const float* input  = (const float*)d_in[0];
    const float* target = (const float*)d_in[1];
    float* out = (float*)d_out;
    float* partial = (float*)d_ws;

    const int B = in_sizes[0] / (30 * 49);         // 16384
    const int ncells = B * 49;                     // 802816
    const int nblocks = (ncells + TPB - 1) / TPB;  // 3136

    yolo_main<<<nblocks, TPB, 0, stream>>>(input, target, partial, ncells);
    yolo_reduce<<<1, 256, 0, stream>>>(partial, nblocks, out, 1.0f / (float)B);
}